// Round 8
// baseline (468.376 us; speedup 1.0000x reference)
//
#include <hip/hip_runtime.h>

// AdaTTSp on MI355X. B=32768, T=8, E=2, NE=16, D=H=128, L=2.
// Round 8: fp16 numerics (weights hi/lo split w/ 2048-scaled lo, activations
// single fp16; 2 MFMAs per term) + 1-sync/expert software pipeline
// (GEMM2(e) ∥ GEMM1(e+1), dbuf sH/sX) + fp16 inter-layer x + LDS-transposed
// coalesced output. 32 rows/block, 512 thr (8 waves), wave = oc 16-tile.

typedef float f32x4 __attribute__((ext_vector_type(4)));
typedef _Float16 f16;
typedef f16 f16x8 __attribute__((ext_vector_type(8)));
typedef f16 f16x4 __attribute__((ext_vector_type(4)));

#define MFMA(a, b, c) __builtin_amdgcn_mfma_f32_16x16x32_f16(a, b, c, 0, 0, 0)
#define LOSC (1.0f / 2048.0f)

__device__ __forceinline__ void split2h(float f, f16& h, f16& l) {
  h = (f16)f;
  l = (f16)((f - (float)h) * 2048.0f);  // scaled into fp16 normal range
}

// ---------------------------------------------------------------------------
// Weight transform -> fp16 hi/lo fragment arrays (lo scaled by 2048).
// w1T/w2T: [q=l*16+e][ks][it][lane][j] (lo at +524288 f16)
//   elem = w[q][d = 32*ks + 8*(lane>>4) + j][m = 16*it + (lane&15)]
// gwT: [q=l*8+t][ks][lane][j] (lo at +32768)
__global__ __launch_bounds__(256) void kxform(
    const float* __restrict__ w1, const float* __restrict__ w2,
    const float* __restrict__ gw, f16* __restrict__ w1T,
    f16* __restrict__ w2T, f16* __restrict__ gwT) {
  int idx = blockIdx.x * 256 + threadIdx.x;
  if (idx < 131072) {
    const float* src = (idx < 65536) ? w1 : w2;
    f16* dst = (idx < 65536) ? w1T : w2T;
    int i = idx & 65535;
    int lane = i & 63;
    int it = (i >> 6) & 7;
    int ks = (i >> 9) & 3;
    int q = i >> 11;
    int g = lane >> 4, le = lane & 15;
    f16x8 vh, vl;
#pragma unroll
    for (int j = 0; j < 8; ++j) {
      float f = src[((size_t)q * 128 + (32 * ks + 8 * g + j)) * 128 + 16 * it + le];
      f16 h, l;
      split2h(f, h, l);
      vh[j] = h;
      vl[j] = l;
    }
    *(f16x8*)(dst + (size_t)i * 8) = vh;
    *(f16x8*)(dst + 524288 + (size_t)i * 8) = vl;
  } else {
    int i = idx - 131072;
    if (i >= 4096) return;
    int lane = i & 63;
    int ks = (i >> 6) & 3;
    int q = (i >> 8) & 15;
    int g = lane >> 4, le = lane & 15;
    f16x8 vh, vl;
#pragma unroll
    for (int j = 0; j < 8; ++j) {
      float f = gw[((size_t)q * 128 + (32 * ks + 8 * g + j)) * 16 + le];
      f16 h, l;
      split2h(f, h, l);
      vh[j] = h;
      vl[j] = l;
    }
    *(f16x8*)(gwT + (size_t)i * 8) = vh;
    *(f16x8*)(gwT + 32768 + (size_t)i * 8) = vl;
  }
}

// ---------------------------------------------------------------------------
// Fused layer kernel. grid = 1024 blocks (32 rows), 512 threads (8 waves).
// LDS x/h tiles: elem [row][c] at row*128 + 8*((c>>3)^(row&7)) + (c&7).
__global__ __launch_bounds__(512, 4) void kfused(
    const float* __restrict__ x0, const f16* __restrict__ x1in,
    f16* __restrict__ x1out, float* __restrict__ fout,
    const f16* __restrict__ w1T, const f16* __restrict__ w2T,
    const f16* __restrict__ gwT, const float* __restrict__ b1,
    const float* __restrict__ b2, const float* __restrict__ gb,
    const float* __restrict__ sw, int layer) {
  __shared__ __align__(16) unsigned char smem[49152];
  f16* sX0 = (f16*)smem;              // [2][4096] fp16, 16KB
  f16* sH0 = (f16*)(smem + 16384);    // [2][4096] fp16, 16KB
  float* sG = (float*)(smem + 32768); // [t][e][row32] f32, 16KB
  float* sT = (float*)smem;           // transpose: [32][260] f32 (post-loop)

  const int tid = threadIdx.x;
  const int lane = tid & 63;
  const int it = tid >> 6;  // wave = oc 16-tile
  const int g = lane >> 4, le = lane & 15;
  const int r0 = blockIdx.x * 32;

  // ---- stage one task slice (32 rows x 128) into sX[buf] ----
  auto stage = [&](int buf, int te) {
    int row = tid >> 4, c8 = tid & 15;
    f16x8 v;
    if (layer == 0) {
      const float* p = x0 + ((size_t)(r0 + row) * 8 + te) * 128 + c8 * 8;
      f32x4 f0 = *(const f32x4*)p;
      f32x4 f1 = *(const f32x4*)(p + 4);
#pragma unroll
      for (int z = 0; z < 4; ++z) {
        v[z] = (f16)f0[z];
        v[4 + z] = (f16)f1[z];
      }
    } else {
      v = *(const f16x8*)(x1in + ((size_t)(r0 + row) * 8 + te) * 128 + c8 * 8);
    }
    *(f16x8*)(sX0 + buf * 4096 + row * 128 + 8 * (c8 ^ (row & 7))) = v;
  };

  // ---- GEMM1(e1): h = relu(w1^T x^T + b1) -> sH[e1&1] ----
  auto gemm1 = [&](int e1) {
    const int lx = layer * 16 + e1;
    const f16* sx = sX0 + ((e1 >> 1) & 1) * 4096;
    f16* sh = sH0 + (e1 & 1) * 4096;
    f32x4 a1[2], a2[2];
#pragma unroll
    for (int j = 0; j < 2; ++j) {
      a1[j] = f32x4{0.f, 0.f, 0.f, 0.f};
      a2[j] = f32x4{0.f, 0.f, 0.f, 0.f};
    }
#pragma unroll
    for (int ks = 0; ks < 4; ++ks) {
      size_t fb = ((size_t)((lx * 4 + ks) * 8 + it) * 64 + lane) * 8;
      f16x8 ah = *(const f16x8*)(w1T + fb);
      f16x8 al = *(const f16x8*)(w1T + 524288 + fb);
#pragma unroll
      for (int j = 0; j < 2; ++j) {
        int brow = 16 * j + le;
        f16x8 b = *(const f16x8*)(sx + brow * 128 + 8 * ((4 * ks + g) ^ (brow & 7)));
        a1[j] = MFMA(ah, b, a1[j]);
        a2[j] = MFMA(al, b, a2[j]);
      }
    }
    f32x4 bv = *(const f32x4*)(b1 + lx * 128 + 16 * it + 4 * g);
#pragma unroll
    for (int j = 0; j < 2; ++j) {
      int brow = 16 * j + le;
      f16x4 hv;
#pragma unroll
      for (int r = 0; r < 4; ++r)
        hv[r] = (f16)fmaxf(a1[j][r] + a2[j][r] * LOSC + bv[r], 0.f);
      *(f16x4*)(sh + brow * 128 + 8 * ((2 * it + (g >> 1)) ^ (brow & 7)) +
                4 * (g & 1)) = hv;
    }
  };

  // ---- persistent fused accumulators ----
  f32x4 accf[8][2];
#pragma unroll
  for (int t = 0; t < 8; ++t)
#pragma unroll
    for (int j = 0; j < 2; ++j) accf[t][j] = f32x4{0.f, 0.f, 0.f, 0.f};

  // ---- GEMM2(e2) + mix-accumulate ----
  auto gemm2mix = [&](int e2) {
    const int lx = layer * 16 + e2;
    const int te = e2 >> 1, eh = e2 & 1;
    const f16* sh = sH0 + (e2 & 1) * 4096;
    f32x4 a1[2], a2[2];
#pragma unroll
    for (int j = 0; j < 2; ++j) {
      a1[j] = f32x4{0.f, 0.f, 0.f, 0.f};
      a2[j] = f32x4{0.f, 0.f, 0.f, 0.f};
    }
#pragma unroll
    for (int ks = 0; ks < 4; ++ks) {
      size_t fb = ((size_t)((lx * 4 + ks) * 8 + it) * 64 + lane) * 8;
      f16x8 ah = *(const f16x8*)(w2T + fb);
      f16x8 al = *(const f16x8*)(w2T + 524288 + fb);
#pragma unroll
      for (int j = 0; j < 2; ++j) {
        int brow = 16 * j + le;
        f16x8 b = *(const f16x8*)(sh + brow * 128 + 8 * ((4 * ks + g) ^ (brow & 7)));
        a1[j] = MFMA(ah, b, a1[j]);
        a2[j] = MFMA(al, b, a2[j]);
      }
    }
    f32x4 bv = *(const f32x4*)(b2 + lx * 128 + 16 * it + 4 * g);
    float ssew = sw[(layer * 8 + te) * 2 + eh];
#pragma unroll
    for (int j = 0; j < 2; ++j) {
      int brow = 16 * j + le;
      f32x4 ev;
#pragma unroll
      for (int r = 0; r < 4; ++r)
        ev[r] = fmaxf(a1[j][r] + a2[j][r] * LOSC + bv[r], 0.f);
#pragma unroll
      for (int t = 0; t < 8; ++t) {
        float coef = sG[(t * 16 + e2) * 32 + brow] + (t == te ? ssew : 0.f);
#pragma unroll
        for (int r = 0; r < 4; ++r)
          accf[t][j][r] = fmaf(coef, ev[r], accf[t][j][r]);
      }
    }
  };

  // ================= prologue =================
  stage(0, 0);
  {  // gate pass: wave = task t = it; B-frags straight from global
    const int t = it;
    const int lt = layer * 8 + t;
    f32x4 l1[2], l2[2];
#pragma unroll
    for (int j = 0; j < 2; ++j) {
      l1[j] = f32x4{0.f, 0.f, 0.f, 0.f};
      l2[j] = f32x4{0.f, 0.f, 0.f, 0.f};
    }
#pragma unroll
    for (int ks = 0; ks < 4; ++ks) {
      size_t fb = ((size_t)(lt * 4 + ks) * 64 + lane) * 8;
      f16x8 ah = *(const f16x8*)(gwT + fb);
      f16x8 al = *(const f16x8*)(gwT + 32768 + fb);
#pragma unroll
      for (int j = 0; j < 2; ++j) {
        size_t xoff = ((size_t)(r0 + 16 * j + le) * 8 + t) * 128 + 32 * ks + 8 * g;
        f16x8 b;
        if (layer == 0) {
          f32x4 f0 = *(const f32x4*)(x0 + xoff);
          f32x4 f1 = *(const f32x4*)(x0 + xoff + 4);
#pragma unroll
          for (int z = 0; z < 4; ++z) {
            b[z] = (f16)f0[z];
            b[4 + z] = (f16)f1[z];
          }
        } else {
          b = *(const f16x8*)(x1in + xoff);
        }
        l1[j] = MFMA(ah, b, l1[j]);
        l2[j] = MFMA(al, b, l2[j]);
      }
    }
    // C-frag: row(4g+r)=e, col(le)=brow. Softmax over e.
#pragma unroll
    for (int j = 0; j < 2; ++j) {
      float zb[4];
#pragma unroll
      for (int r = 0; r < 4; ++r)
        zb[r] = l1[j][r] + l2[j][r] * LOSC + gb[lt * 16 + 4 * g + r];
      float m4 = fmaxf(fmaxf(zb[0], zb[1]), fmaxf(zb[2], zb[3]));
      m4 = fmaxf(m4, __shfl_xor(m4, 16, 64));
      m4 = fmaxf(m4, __shfl_xor(m4, 32, 64));
      float p4[4], s4 = 0.f;
#pragma unroll
      for (int r = 0; r < 4; ++r) {
        p4[r] = __expf(zb[r] - m4);
        s4 += p4[r];
      }
      s4 += __shfl_xor(s4, 16, 64);
      s4 += __shfl_xor(s4, 32, 64);
      float inv = 1.f / s4;
#pragma unroll
      for (int r = 0; r < 4; ++r)
        sG[(t * 16 + 4 * g + r) * 32 + 16 * j + le] = p4[r] * inv;
    }
  }
  __syncthreads();  // sX[0] + sG ready

  gemm1(0);
  stage(1, 1);
  __syncthreads();

  // ================= main loop: 1 sync per expert =================
  for (int e = 0; e < 16; ++e) {
    if ((e & 1) == 0 && e <= 12) stage((e / 2 + 1) & 1, e / 2 + 1);
    gemm2mix(e);
    if (e < 15) gemm1(e + 1);
    __syncthreads();
  }

  // ================= output via LDS transpose (row stride 260 f32) ========
#pragma unroll
  for (int tt = 0; tt < 4; ++tt) {
#pragma unroll
    for (int tl = 0; tl < 2; ++tl) {
#pragma unroll
      for (int j = 0; j < 2; ++j) {
        int row = 16 * j + le;
        int p = tl * 32 + 4 * it + g;  // semantic granule within 256-col round
        *(f32x4*)(&sT[row * 260 + 4 * p]) = accf[2 * tt + tl][j];
      }
    }
    __syncthreads();
    {
      int row = tid >> 4, c8 = tid & 15;
#pragma unroll
      for (int k = 0; k < 4; ++k) {
        f32x4 v = *(const f32x4*)(&sT[row * 260 + 4 * (4 * c8 + k)]);
        size_t off = (size_t)(r0 + row) * 1024 + tt * 256 + 16 * c8 + 4 * k;
        if (layer == 0) {
          f16x4 hv;
#pragma unroll
          for (int r = 0; r < 4; ++r) hv[r] = (f16)v[r];
          *(f16x4*)(x1out + off) = hv;
        } else {
          *(f32x4*)(fout + off) = v;
        }
      }
    }
    if (tt < 3) __syncthreads();
  }
}

// ---------------------------------------------------------------------------
extern "C" void kernel_launch(void* const* d_in, const int* in_sizes, int n_in,
                              void* d_out, int out_size, void* d_ws, size_t ws_size,
                              hipStream_t stream) {
  const float* x0 = (const float*)d_in[0];
  const float* w1 = (const float*)d_in[1];
  const float* b1 = (const float*)d_in[2];
  const float* w2 = (const float*)d_in[3];
  const float* b2 = (const float*)d_in[4];
  const float* gw = (const float*)d_in[5];
  const float* gb = (const float*)d_in[6];
  const float* sw = (const float*)d_in[7];

  // ws bytes: w1T pair [0,2MB) | w2T pair [2MB,4MB) | gwT pair [4MB,+128KB)
  // | x1h fp16 [8MB, +64MB)
  f16* w1T = (f16*)d_ws;
  f16* w2T = (f16*)((char*)d_ws + 2097152);
  f16* gwT = (f16*)((char*)d_ws + 4194304);
  f16* x1h = (f16*)((char*)d_ws + 8388608);
  float* out = (float*)d_out;

  kxform<<<528, 256, 0, stream>>>(w1, w2, gw, w1T, w2T, gwT);
  kfused<<<1024, 512, 0, stream>>>(x0, nullptr, x1h, nullptr, w1T, w2T, gwT,
                                   b1, b2, gb, sw, 0);
  kfused<<<1024, 512, 0, stream>>>(nullptr, x1h, nullptr, out, w1T, w2T, gwT,
                                   b1, b2, gb, sw, 1);
}

// Round 11
// 338.083 us; speedup vs baseline: 1.3854x; 1.3854x over previous
//
#include <hip/hip_runtime.h>

// AdaTTSp on MI355X. B=32768, T=8, E=2, NE=16, D=H=128, L=2.
// Round 11 = round 9 resubmitted verbatim (rounds 9/10 hit the same dead
// container "spare-cold-late-sword" before compile/run; no data yet).
// Design under test:
//  - expert-major kexp with ALL weight fragments resident in registers
//    (zero weight loads in the row loop; fixes r6-r8's weight-latency disease)
//  - wave = 32 oc-cols (each LDS b-frag read feeds 4 MFMAs), 64-row dbuf tiles
//  - eo -> HBM fp16 (L3-resident 128MB), consumed by kmix (gates + VALU mix)
// Numerics unchanged from r8: fp16 hi/lo weights (lo x2048), fp16 activations.

typedef float f32x4 __attribute__((ext_vector_type(4)));
typedef _Float16 f16;
typedef f16 f16x8 __attribute__((ext_vector_type(8)));
typedef f16 f16x4 __attribute__((ext_vector_type(4)));

#define MFMA(a, b, c) __builtin_amdgcn_mfma_f32_16x16x32_f16(a, b, c, 0, 0, 0)
#define LOSC (1.0f / 2048.0f)

__device__ __forceinline__ void split2h(float f, f16& h, f16& l) {
  h = (f16)f;
  l = (f16)((f - (float)h) * 2048.0f);
}

// ---------------------------------------------------------------------------
// Weight transform -> fp16 hi/lo fragment arrays (identical to round 8).
// w1T/w2T: [q=l*16+e][ks][it][lane][j] (lo at +524288 f16)
//   elem = w[q][d = 32*ks + 8*(lane>>4) + j][m = 16*it + (lane&15)]
// gwT: [q=l*8+t][ks][lane][j] (lo at +32768)
__global__ __launch_bounds__(256) void kxform(
    const float* __restrict__ w1, const float* __restrict__ w2,
    const float* __restrict__ gw, f16* __restrict__ w1T,
    f16* __restrict__ w2T, f16* __restrict__ gwT) {
  int idx = blockIdx.x * 256 + threadIdx.x;
  if (idx < 131072) {
    const float* src = (idx < 65536) ? w1 : w2;
    f16* dst = (idx < 65536) ? w1T : w2T;
    int i = idx & 65535;
    int lane = i & 63;
    int it = (i >> 6) & 7;
    int ks = (i >> 9) & 3;
    int q = i >> 11;
    int g = lane >> 4, le = lane & 15;
    f16x8 vh, vl;
#pragma unroll
    for (int j = 0; j < 8; ++j) {
      float f = src[((size_t)q * 128 + (32 * ks + 8 * g + j)) * 128 + 16 * it + le];
      f16 h, l;
      split2h(f, h, l);
      vh[j] = h;
      vl[j] = l;
    }
    *(f16x8*)(dst + (size_t)i * 8) = vh;
    *(f16x8*)(dst + 524288 + (size_t)i * 8) = vl;
  } else {
    int i = idx - 131072;
    if (i >= 4096) return;
    int lane = i & 63;
    int ks = (i >> 6) & 3;
    int q = (i >> 8) & 15;
    int g = lane >> 4, le = lane & 15;
    f16x8 vh, vl;
#pragma unroll
    for (int j = 0; j < 8; ++j) {
      float f = gw[((size_t)q * 128 + (32 * ks + 8 * g + j)) * 16 + le];
      f16 h, l;
      split2h(f, h, l);
      vh[j] = h;
      vl[j] = l;
    }
    *(f16x8*)(gwT + (size_t)i * 8) = vh;
    *(f16x8*)(gwT + 32768 + (size_t)i * 8) = vl;
  }
}

// ---------------------------------------------------------------------------
// Expert kernel. grid = 32 chunks(1024 rows) x 16 experts; 256 thr (4 waves).
// Wave = it2 (oc 32-col tile). Weights in regs: w{1,2}{h,l}[i2][ks] = 128 reg.
// Per 64-row tile: GEMM1 (64 MFMA/wave) -> sH -> GEMM2 (64) -> eo fp16.
// LDS x/h swizzle: elem [row][c] at row*128 + 8*((c>>3)^(row&7)) + (c&7).
__global__ __launch_bounds__(256, 2) void kexp(
    const float* __restrict__ x0, const f16* __restrict__ x1in,
    const f16* __restrict__ w1T, const f16* __restrict__ w2T,
    const float* __restrict__ b1, const float* __restrict__ b2,
    f16* __restrict__ eo, int layer) {
  __shared__ f16 sX[2][8192];  // 64 x 128, double-buffered (32KB)
  __shared__ f16 sH[8192];     // 16KB
  const int tid = threadIdx.x;
  const int lane = tid & 63;
  const int it2 = tid >> 6;
  const int g = lane >> 4, le = lane & 15;
  const int e = blockIdx.x & 15;
  const int r0 = (blockIdx.x >> 4) * 1024;
  const int te = e >> 1;
  const int lx = layer * 16 + e;

  // ---- resident weight fragments (it = 2*it2 + i2) ----
  f16x8 w1h[2][4], w1l[2][4], w2h[2][4], w2l[2][4];
#pragma unroll
  for (int i2 = 0; i2 < 2; ++i2)
#pragma unroll
    for (int ks = 0; ks < 4; ++ks) {
      size_t fb = ((size_t)((lx * 4 + ks) * 8 + 2 * it2 + i2) * 64 + lane) * 8;
      w1h[i2][ks] = *(const f16x8*)(w1T + fb);
      w1l[i2][ks] = *(const f16x8*)(w1T + 524288 + fb);
      w2h[i2][ks] = *(const f16x8*)(w2T + fb);
      w2l[i2][ks] = *(const f16x8*)(w2T + 524288 + fb);
    }
  f32x4 b1v[2], b2v[2];
#pragma unroll
  for (int i2 = 0; i2 < 2; ++i2) {
    b1v[i2] = *(const f32x4*)(b1 + lx * 128 + 32 * it2 + 16 * i2 + 4 * g);
    b2v[i2] = *(const f32x4*)(b2 + lx * 128 + 32 * it2 + 16 * i2 + 4 * g);
  }

  // ---- stage 64 rows x 128 cols of this task's x slice ----
  auto stage = [&](int buf, int tile) {
    int row = tid >> 2;
    int G0 = (tid & 3) * 4;
    size_t gbase = ((size_t)(r0 + tile * 64 + row) * 8 + te) * 128 + G0 * 8;
    f16* dst = &sX[buf][row * 128];
#pragma unroll
    for (int q = 0; q < 4; ++q) {
      f16x8 v;
      if (layer == 0) {
        f32x4 f0 = *(const f32x4*)(x0 + gbase + q * 8);
        f32x4 f1 = *(const f32x4*)(x0 + gbase + q * 8 + 4);
#pragma unroll
        for (int z = 0; z < 4; ++z) {
          v[z] = (f16)f0[z];
          v[4 + z] = (f16)f1[z];
        }
      } else {
        v = *(const f16x8*)(x1in + gbase + q * 8);
      }
      *(f16x8*)(dst + 8 * ((G0 + q) ^ (row & 7))) = v;
    }
  };

  stage(0, 0);
  __syncthreads();

  for (int tile = 0; tile < 16; ++tile) {
    const int b = tile & 1;
    // ---- GEMM1: h = relu(w1^T x^T + b1) -> sH ----
    {
      f32x4 a1[2][4], a2[2][4];
#pragma unroll
      for (int i2 = 0; i2 < 2; ++i2)
#pragma unroll
        for (int j = 0; j < 4; ++j) {
          a1[i2][j] = f32x4{0.f, 0.f, 0.f, 0.f};
          a2[i2][j] = f32x4{0.f, 0.f, 0.f, 0.f};
        }
#pragma unroll
      for (int ks = 0; ks < 4; ++ks)
#pragma unroll
        for (int j = 0; j < 4; ++j) {
          int brow = 16 * j + le;
          f16x8 bf = *(const f16x8*)(&sX[b][brow * 128 + 8 * ((4 * ks + g) ^ (brow & 7))]);
#pragma unroll
          for (int i2 = 0; i2 < 2; ++i2) {
            a1[i2][j] = MFMA(w1h[i2][ks], bf, a1[i2][j]);
            a2[i2][j] = MFMA(w1l[i2][ks], bf, a2[i2][j]);
          }
        }
#pragma unroll
      for (int i2 = 0; i2 < 2; ++i2)
#pragma unroll
        for (int j = 0; j < 4; ++j) {
          int brow = 16 * j + le;
          f16x4 hv;
#pragma unroll
          for (int r = 0; r < 4; ++r)
            hv[r] = (f16)fmaxf(a1[i2][j][r] + a2[i2][j][r] * LOSC + b1v[i2][r], 0.f);
          *(f16x4*)(&sH[brow * 128 + 8 * ((4 * it2 + 2 * i2 + (g >> 1)) ^ (brow & 7)) +
                        4 * (g & 1)]) = hv;
        }
    }
    __syncthreads();
    // ---- stage next tile (loads fly under GEMM2) ----
    if (tile < 15) stage(b ^ 1, tile + 1);
    // ---- GEMM2: eo = relu(w2^T h^T + b2) -> global fp16 ----
    {
      f32x4 a1[2][4], a2[2][4];
#pragma unroll
      for (int i2 = 0; i2 < 2; ++i2)
#pragma unroll
        for (int j = 0; j < 4; ++j) {
          a1[i2][j] = f32x4{0.f, 0.f, 0.f, 0.f};
          a2[i2][j] = f32x4{0.f, 0.f, 0.f, 0.f};
        }
#pragma unroll
      for (int ks = 0; ks < 4; ++ks)
#pragma unroll
        for (int j = 0; j < 4; ++j) {
          int brow = 16 * j + le;
          f16x8 bf = *(const f16x8*)(&sH[brow * 128 + 8 * ((4 * ks + g) ^ (brow & 7))]);
#pragma unroll
          for (int i2 = 0; i2 < 2; ++i2) {
            a1[i2][j] = MFMA(w2h[i2][ks], bf, a1[i2][j]);
            a2[i2][j] = MFMA(w2l[i2][ks], bf, a2[i2][j]);
          }
        }
#pragma unroll
      for (int i2 = 0; i2 < 2; ++i2)
#pragma unroll
        for (int j = 0; j < 4; ++j) {
          int grow = r0 + tile * 64 + 16 * j + le;
          f16x4 ev;
#pragma unroll
          for (int r = 0; r < 4; ++r)
            ev[r] = (f16)fmaxf(a1[i2][j][r] + a2[i2][j][r] * LOSC + b2v[i2][r], 0.f);
          *(f16x4*)(eo + ((size_t)grow * 16 + e) * 128 + 32 * it2 + 16 * i2 + 4 * g) = ev;
        }
    }
    __syncthreads();
  }
}

// ---------------------------------------------------------------------------
// Gate + mix kernel. grid = 1024 blocks (32 rows), 512 thr (8 waves).
// Phase 1: wave = task, gate MFMA (B-frags from global x) + shfl softmax.
// Phase 2: thread = (row = tid>>4, 8 cols = (tid&15)*8): mix over 16 experts.
__global__ __launch_bounds__(512, 4) void kmix(
    const float* __restrict__ x0, const f16* __restrict__ x1in,
    const f16* __restrict__ gwT, const float* __restrict__ gb,
    const float* __restrict__ sw, const f16* __restrict__ eo,
    f16* __restrict__ x1out, float* __restrict__ fout, int layer) {
  __shared__ float sG[8 * 16 * 32];  // [t][e][row32] 16KB
  const int tid = threadIdx.x;
  const int lane = tid & 63;
  const int t = tid >> 6;  // wave = task
  const int g = lane >> 4, le = lane & 15;
  const int r0 = blockIdx.x * 32;
  const int lt = layer * 8 + t;

  {  // ---- gates ----
    f32x4 l1[2], l2[2];
#pragma unroll
    for (int j = 0; j < 2; ++j) {
      l1[j] = f32x4{0.f, 0.f, 0.f, 0.f};
      l2[j] = f32x4{0.f, 0.f, 0.f, 0.f};
    }
#pragma unroll
    for (int ks = 0; ks < 4; ++ks) {
      size_t fb = ((size_t)(lt * 4 + ks) * 64 + lane) * 8;
      f16x8 ah = *(const f16x8*)(gwT + fb);
      f16x8 al = *(const f16x8*)(gwT + 32768 + fb);
#pragma unroll
      for (int j = 0; j < 2; ++j) {
        size_t xoff = ((size_t)(r0 + 16 * j + le) * 8 + t) * 128 + 32 * ks + 8 * g;
        f16x8 bf;
        if (layer == 0) {
          f32x4 f0 = *(const f32x4*)(x0 + xoff);
          f32x4 f1 = *(const f32x4*)(x0 + xoff + 4);
#pragma unroll
          for (int z = 0; z < 4; ++z) {
            bf[z] = (f16)f0[z];
            bf[4 + z] = (f16)f1[z];
          }
        } else {
          bf = *(const f16x8*)(x1in + xoff);
        }
        l1[j] = MFMA(ah, bf, l1[j]);
        l2[j] = MFMA(al, bf, l2[j]);
      }
    }
#pragma unroll
    for (int j = 0; j < 2; ++j) {
      float zb[4];
#pragma unroll
      for (int r = 0; r < 4; ++r)
        zb[r] = l1[j][r] + l2[j][r] * LOSC + gb[lt * 16 + 4 * g + r];
      float m4 = fmaxf(fmaxf(zb[0], zb[1]), fmaxf(zb[2], zb[3]));
      m4 = fmaxf(m4, __shfl_xor(m4, 16, 64));
      m4 = fmaxf(m4, __shfl_xor(m4, 32, 64));
      float p4[4], s4 = 0.f;
#pragma unroll
      for (int r = 0; r < 4; ++r) {
        p4[r] = __expf(zb[r] - m4);
        s4 += p4[r];
      }
      s4 += __shfl_xor(s4, 16, 64);
      s4 += __shfl_xor(s4, 32, 64);
      float inv = 1.f / s4;
#pragma unroll
      for (int r = 0; r < 4; ++r)
        sG[(t * 16 + 4 * g + r) * 32 + 16 * j + le] = p4[r] * inv;
    }
  }
  __syncthreads();

  // ---- mix ----
  const int lrow = tid >> 4;
  const int grow = r0 + lrow;
  const int c0 = (tid & 15) * 8;
  f32x4 am[8][2];
#pragma unroll
  for (int tt = 0; tt < 8; ++tt)
#pragma unroll
    for (int k = 0; k < 2; ++k) am[tt][k] = f32x4{0.f, 0.f, 0.f, 0.f};

  for (int e = 0; e < 16; ++e) {
    const int te = e >> 1, eh = e & 1;
    f16x8 ev = *(const f16x8*)(eo + ((size_t)grow * 16 + e) * 128 + c0);
    float evf[8];
#pragma unroll
    for (int z = 0; z < 8; ++z) evf[z] = (float)ev[z];
    float ssew = sw[(layer * 8 + te) * 2 + eh];
#pragma unroll
    for (int tt = 0; tt < 8; ++tt) {
      float coef = sG[(tt * 16 + e) * 32 + lrow] + (tt == te ? ssew : 0.f);
#pragma unroll
      for (int z = 0; z < 8; ++z)
        am[tt][z >> 2][z & 3] = fmaf(coef, evf[z], am[tt][z >> 2][z & 3]);
    }
  }
#pragma unroll
  for (int tt = 0; tt < 8; ++tt) {
    size_t off = ((size_t)grow * 8 + tt) * 128 + c0;
    if (layer == 0) {
      f16x8 hv;
#pragma unroll
      for (int z = 0; z < 8; ++z) hv[z] = (f16)am[tt][z >> 2][z & 3];
      *(f16x8*)(x1out + off) = hv;
    } else {
      *(f32x4*)(fout + off) = am[tt][0];
      *(f32x4*)(fout + off + 4) = am[tt][1];
    }
  }
}

// ---------------------------------------------------------------------------
extern "C" void kernel_launch(void* const* d_in, const int* in_sizes, int n_in,
                              void* d_out, int out_size, void* d_ws, size_t ws_size,
                              hipStream_t stream) {
  const float* x0 = (const float*)d_in[0];
  const float* w1 = (const float*)d_in[1];
  const float* b1 = (const float*)d_in[2];
  const float* w2 = (const float*)d_in[3];
  const float* b2 = (const float*)d_in[4];
  const float* gw = (const float*)d_in[5];
  const float* gb = (const float*)d_in[6];
  const float* sw = (const float*)d_in[7];

  // ws bytes: w1T pair [0,2MB) | w2T pair [2MB,4MB) | gwT pair [4MB,+128KB)
  // | x1h fp16 [8MB,+64MB) | eo fp16 [80MB,+128MB)
  f16* w1T = (f16*)d_ws;
  f16* w2T = (f16*)((char*)d_ws + 2097152);
  f16* gwT = (f16*)((char*)d_ws + 4194304);
  f16* x1h = (f16*)((char*)d_ws + 8388608);
  f16* eo = (f16*)((char*)d_ws + 83886080);
  float* out = (float*)d_out;

  kxform<<<528, 256, 0, stream>>>(w1, w2, gw, w1T, w2T, gwT);

  kexp<<<512, 256, 0, stream>>>(x0, nullptr, w1T, w2T, b1, b2, eo, 0);
  kmix<<<1024, 512, 0, stream>>>(x0, nullptr, gwT, gb, sw, eo, x1h, nullptr, 0);
  kexp<<<512, 256, 0, stream>>>(nullptr, x1h, w1T, w2T, b1, b2, eo, 1);
  kmix<<<1024, 512, 0, stream>>>(nullptr, x1h, gwT, gb, sw, eo, nullptr, out, 1);
}